// Round 6
// baseline (2743.752 us; speedup 1.0000x reference)
//
#include <hip/hip_runtime.h>
#include <math.h>

#define NN 50000
#define NE 800000
#define NG 64
#define DIN 64
#define DEA 16
#define H 128
#define NL 4
#define EPB 128      // edges per block in agg_gemm_kernel
#define EC 160000    // edges per chunk (5 chunks; t buffer = EC*128*2B = 41MB)

typedef __attribute__((ext_vector_type(8))) short short8;
typedef __attribute__((ext_vector_type(4))) float f32x4;

__device__ __forceinline__ float4 ld4(const float* p) { return *reinterpret_cast<const float4*>(p); }
__device__ __forceinline__ void st4(float* p, float4 v) { *reinterpret_cast<float4*>(p) = v; }
__device__ __forceinline__ void fma4(float4& a, float s, float4 w) {
    a.x = fmaf(s, w.x, a.x); a.y = fmaf(s, w.y, a.y);
    a.z = fmaf(s, w.z, a.z); a.w = fmaf(s, w.w, a.w);
}
__device__ __forceinline__ float4 f4add(float4 a, float4 b) {
    return make_float4(a.x + b.x, a.y + b.y, a.z + b.z, a.w + b.w);
}
__device__ __forceinline__ float4 relu4(float4 a) {
    return make_float4(fmaxf(a.x, 0.f), fmaxf(a.y, 0.f), fmaxf(a.z, 0.f), fmaxf(a.w, 0.f));
}
__device__ __forceinline__ unsigned fkey(float f) {
    unsigned b = __float_as_uint(f);
    return (b & 0x80000000u) ? ~b : (b | 0x80000000u);
}
__device__ __forceinline__ float funkey(unsigned k) {
    unsigned b = (k & 0x80000000u) ? (k ^ 0x80000000u) : ~k;
    return __uint_as_float(b);
}
__device__ __forceinline__ ushort f2bf(float f) {
    unsigned u = __float_as_uint(f);
    return (ushort)((u + 0x7fffu + ((u >> 16) & 1u)) >> 16);
}
__device__ __forceinline__ float bf2f(ushort b) {
    return __uint_as_float(((unsigned)b) << 16);
}

// h = relu(x @ encW + encb), x:[NN,64], W:[64,128]
__global__ __launch_bounds__(256) void encoder_kernel(const float* __restrict__ x,
    const float* __restrict__ W, const float* __restrict__ b, float* __restrict__ h)
{
    const int tid = threadIdx.x, q = tid & 31, no = tid >> 5;
    const int nbase = blockIdx.x * 64;
    float4 bv = ld4(b + 4 * q);
    float4 acc[8];
#pragma unroll
    for (int i = 0; i < 8; ++i) acc[i] = bv;
    for (int k4 = 0; k4 < 16; ++k4) {
        const float* wp = W + (4 * k4) * H + 4 * q;
        float4 w0 = ld4(wp), w1 = ld4(wp + H), w2 = ld4(wp + 2 * H), w3 = ld4(wp + 3 * H);
#pragma unroll
        for (int i = 0; i < 8; ++i) {
            int n = nbase + no * 8 + i; n = n < NN ? n : NN - 1;
            float4 a = ld4(x + n * DIN + 4 * k4);
            fma4(acc[i], a.x, w0); fma4(acc[i], a.y, w1);
            fma4(acc[i], a.z, w2); fma4(acc[i], a.w, w3);
        }
    }
#pragma unroll
    for (int i = 0; i < 8; ++i) {
        int n = nbase + no * 8 + i;
        if (n < NN) st4(h + n * H + 4 * q, relu4(acc[i]));
    }
}

__global__ __launch_bounds__(256) void dist2_kernel(const float* __restrict__ pos,
    const int* __restrict__ ei, float* __restrict__ d2)
{
    int e = blockIdx.x * 256 + threadIdx.x;
    if (e >= NE) return;
    int s = ei[e], d = ei[NE + e];
    float dx = pos[s * 3 + 0] - pos[d * 3 + 0];
    float dy = pos[s * 3 + 1] - pos[d * 3 + 1];
    float dz = pos[s * 3 + 2] - pos[d * 3 + 2];
    d2[e] = dx * dx + dy * dy + dz * dz;
}

// ---------- counting sort of edges by dst ----------
__global__ __launch_bounds__(256) void hist_kernel(const int* __restrict__ ei, int* __restrict__ deg)
{
    int e = blockIdx.x * 256 + threadIdx.x;
    if (e < NE) atomicAdd(&deg[ei[NE + e]], 1);
}

__global__ __launch_bounds__(256) void scan_kernel(const int* __restrict__ deg, int* __restrict__ cursor)
{
    __shared__ int tot[256];
    const int t = threadIdx.x;
    const int CH = (NN + 255) / 256;
    const int base = t * CH;
    int s = 0;
    for (int i = 0; i < CH; ++i) {
        int idx = base + i;
        if (idx < NN) s += deg[idx];
    }
    tot[t] = s;
    __syncthreads();
    for (int off = 1; off < 256; off <<= 1) {
        int v = (t >= off) ? tot[t - off] : 0;
        __syncthreads();
        tot[t] += v;
        __syncthreads();
    }
    int run = (t == 0) ? 0 : tot[t - 1];
    for (int i = 0; i < CH; ++i) {
        int idx = base + i;
        if (idx < NN) { cursor[idx] = run; run += deg[idx]; }
    }
}

__global__ __launch_bounds__(256) void scatter_kernel(const int* __restrict__ ei,
    const float* __restrict__ ea, const float* __restrict__ d2, int* __restrict__ cursor,
    int* __restrict__ src_s, int* __restrict__ dst_s,
    float* __restrict__ ea_s, float* __restrict__ d2_s)
{
    int e = blockIdx.x * 256 + threadIdx.x;
    if (e >= NE) return;
    int s = ei[e], d = ei[NE + e];
    int pos = atomicAdd(&cursor[d], 1);
    src_s[pos] = s; dst_s[pos] = d; d2_s[pos] = d2[e];
    const float4* ev = reinterpret_cast<const float4*>(ea + (size_t)e * DEA);
    float4* ov = reinterpret_cast<float4*>(ea_s + (size_t)pos * DEA);
    ov[0] = ev[0]; ov[1] = ev[1]; ov[2] = ev[2]; ov[3] = ev[3];
}

// ---------- generic W [K x 128] -> split bf16 (hi+lo), transposed [n][k], k-panel-64 swizzled ----------
__global__ __launch_bounds__(256) void wprep_kernel(const float* __restrict__ W,
    ushort* __restrict__ hi, ushort* __restrict__ lo,
    int K, int in_lstride, int out_lstride)
{
    int l = blockIdx.y;
    const float* Wb = W + (size_t)l * in_lstride;
    ushort* hg = hi + (size_t)l * out_lstride;
    ushort* lg = lo + (size_t)l * out_lstride;
    int total = K * 128;
    for (int idx = blockIdx.x * 256 + threadIdx.x; idx < total; idx += gridDim.x * 256) {
        int k = idx >> 7, n = idx & 127;
        float wv = Wb[idx];
        ushort hb = f2bf(wv);
        float rem = wv - bf2f(hb);
        ushort lb = f2bf(rem);
        int panel = k >> 6, kk = k & 63;
        int pos = panel * 8192 + (n << 6) + (kk ^ ((n & 7) << 3));
        hg[pos] = hb; lg[pos] = lb;
    }
}

// ---------- proj: Pdb = bf16(h@W1d + b1), Psb = bf16(h@W1s)  (MFMA, split-bf16 weights) ----------
__global__ __launch_bounds__(512, 4) void proj_mfma_kernel(const float* __restrict__ h,
    const ushort* __restrict__ wdh, const ushort* __restrict__ wdl,
    const ushort* __restrict__ wsh, const ushort* __restrict__ wsl,
    const float* __restrict__ b1,
    ushort* __restrict__ Pdb, ushort* __restrict__ Psb)
{
    __shared__ __align__(16) ushort Afull[128 * 128];  // 32KB
    __shared__ __align__(16) ushort Wh[128 * 64];      // 16KB
    __shared__ __align__(16) ushort Wl[128 * 64];      // 16KB
    const int tid = threadIdx.x;
    const int nbase = blockIdx.x * 128;

    {
        int r = tid >> 2, kq = (tid & 3) * 32;
        int n = nbase + r; n = n < NN ? n : NN - 1;
        const float* src = h + (size_t)n * H + kq;
        int swz = (r & 7) << 3;
#pragma unroll
        for (int j = 0; j < 4; ++j) {
            float4 a = ld4(src + 8 * j);
            float4 b = ld4(src + 8 * j + 4);
            union { ushort u[8]; int4 v; } pk;
            pk.u[0] = f2bf(a.x); pk.u[1] = f2bf(a.y); pk.u[2] = f2bf(a.z); pk.u[3] = f2bf(a.w);
            pk.u[4] = f2bf(b.x); pk.u[5] = f2bf(b.y); pk.u[6] = f2bf(b.z); pk.u[7] = f2bf(b.w);
            *reinterpret_cast<int4*>(&Afull[r * 128 + ((kq + 8 * j) ^ swz)]) = pk.v;
        }
    }

    const int lane = tid & 63, wvx = tid >> 6, colL = lane & 15, g = lane >> 4;
    const int arow = wvx * 16 + colL, aswz = (arow & 7) << 3;
    f32x4 accd[8], accs[8];
#pragma unroll
    for (int nt = 0; nt < 8; ++nt) { accd[nt] = (f32x4){0, 0, 0, 0}; accs[nt] = (f32x4){0, 0, 0, 0}; }

#define PROJ_ROUND(HSRC, LSRC, KOFF, ACC)                                               \
    {                                                                                   \
        ((int4*)Wh)[tid] = ((const int4*)(HSRC))[tid];                                  \
        ((int4*)Wh)[tid + 512] = ((const int4*)(HSRC))[tid + 512];                      \
        ((int4*)Wl)[tid] = ((const int4*)(LSRC))[tid];                                  \
        ((int4*)Wl)[tid + 512] = ((const int4*)(LSRC))[tid + 512];                      \
        __syncthreads();                                                                \
        _Pragma("unroll")                                                               \
        for (int ks = 0; ks < 2; ++ks) {                                                \
            int kk0 = ks * 32;                                                          \
            short8 af = *(const short8*)&Afull[arow * 128 + (((KOFF) + kk0 + 8 * g) ^ aswz)]; \
            _Pragma("unroll")                                                           \
            for (int nt = 0; nt < 8; ++nt) {                                            \
                int brow = nt * 16 + colL;                                              \
                int bidx = brow * 64 + ((kk0 + 8 * g) ^ ((brow & 7) << 3));             \
                short8 bh = *(const short8*)&Wh[bidx];                                  \
                short8 bl = *(const short8*)&Wl[bidx];                                  \
                ACC[nt] = __builtin_amdgcn_mfma_f32_16x16x32_bf16(af, bh, ACC[nt], 0, 0, 0); \
                ACC[nt] = __builtin_amdgcn_mfma_f32_16x16x32_bf16(af, bl, ACC[nt], 0, 0, 0); \
            }                                                                           \
        }                                                                               \
        __syncthreads();                                                                \
    }

    PROJ_ROUND(wdh, wdl, 0, accd)
    PROJ_ROUND(wdh + 8192, wdl + 8192, 64, accd)
    PROJ_ROUND(wsh, wsl, 0, accs)
    PROJ_ROUND(wsh + 8192, wsl + 8192, 64, accs)
#undef PROJ_ROUND

    float b1r[8];
#pragma unroll
    for (int nt = 0; nt < 8; ++nt) b1r[nt] = b1[nt * 16 + colL];

    const int rowb = wvx * 16 + g * 4;
#pragma unroll
    for (int r = 0; r < 4; ++r) {
        int n = nbase + rowb + r;
        if (n < NN) {
#pragma unroll
            for (int nt = 0; nt < 8; ++nt) {
                Pdb[(size_t)n * H + nt * 16 + colL] = f2bf(accd[nt][r] + b1r[nt]);
                Psb[(size_t)n * H + nt * 16 + colL] = f2bf(accs[nt][r]);
            }
        }
    }
}

// ---------- tmsg: t = relu(Pdb[dst] + Psb[src] + d2*wd + ea@Wea), bf16, pre-swizzled ----------
// 256 threads = 32 lanes (4 cols each) x 8 edge slots; 8 edges per slot -> 64 edges/block
__global__ __launch_bounds__(256) void tmsg_kernel(
    const ushort* __restrict__ Pdb, const ushort* __restrict__ Psb,
    const float* __restrict__ ea_c, const float* __restrict__ d2_c,
    const int* __restrict__ src_c, const int* __restrict__ dst_c,
    const float* __restrict__ W1, ushort* __restrict__ t_s)
{
    const int tid = threadIdx.x, q = tid & 31, eslot = tid >> 5;
    const float* Wea = W1 + 256 * H;
    const float* wdv = W1 + 272 * H;
    float4 wea[16];
#pragma unroll
    for (int k = 0; k < 16; ++k) wea[k] = ld4(Wea + k * H + 4 * q);
    float4 wd4 = ld4(wdv + 4 * q);
    const int ebase = blockIdx.x * 64 + eslot * 8;
#pragma unroll
    for (int i = 0; i < 8; ++i) {
        int e = ebase + i;
        int s = src_c[e], d = dst_c[e];
        float d2v = d2_c[e];
        float eav = (q < 16) ? ea_c[(size_t)e * DEA + q] : 0.f;
        ushort4 pd4 = *reinterpret_cast<const ushort4*>(&Pdb[(size_t)d * H + 4 * q]);
        ushort4 ps4 = *reinterpret_cast<const ushort4*>(&Psb[(size_t)s * H + 4 * q]);
        float4 acc;
        acc.x = bf2f(pd4.x) + bf2f(ps4.x);
        acc.y = bf2f(pd4.y) + bf2f(ps4.y);
        acc.z = bf2f(pd4.z) + bf2f(ps4.z);
        acc.w = bf2f(pd4.w) + bf2f(ps4.w);
        fma4(acc, d2v, wd4);
#pragma unroll
        for (int k = 0; k < 16; ++k) {
            float ek = __shfl(eav, k, 32);
            fma4(acc, ek, wea[k]);
        }
        ushort4 tv;
        tv.x = f2bf(fmaxf(acc.x, 0.f)); tv.y = f2bf(fmaxf(acc.y, 0.f));
        tv.z = f2bf(fmaxf(acc.z, 0.f)); tv.w = f2bf(fmaxf(acc.w, 0.f));
        *reinterpret_cast<ushort4*>(&t_s[(size_t)e * H + ((4 * q) ^ ((e & 7) << 3))]) = tv;
    }
}

// ---------- agg GEMM: m = relu(t @ (W2hi+W2lo) + b2), segmented atomic flush to agg ----------
__global__ __launch_bounds__(512, 4) void agg_gemm_kernel(
    const ushort* __restrict__ t_s, const int* __restrict__ dst_c,
    const ushort* __restrict__ w2hiL, const ushort* __restrict__ w2loL,
    const float* __restrict__ b2, float* __restrict__ agg)
{
    __shared__ __align__(16) ushort tls[EPB * H];   // 32KB, pre-swizzled in global
    __shared__ __align__(16) ushort whi[H * 64];    // 16KB
    __shared__ __align__(16) ushort wlo[H * 64];    // 16KB

    const int tid = threadIdx.x;
    const int ebase = blockIdx.x * EPB;

    // sequential t-tile load (reg-staged)
    const int4* tg4 = (const int4*)(t_s + (size_t)ebase * H);
    int4 tr0 = tg4[tid], tr1 = tg4[tid + 512], tr2 = tg4[tid + 1024], tr3 = tg4[tid + 1536];

    const int4* ghi = (const int4*)w2hiL;
    const int4* glo = (const int4*)w2loL;
    int4 rh0[2], rl0[2];
    rh0[0] = ghi[tid]; rh0[1] = ghi[tid + 512];
    rl0[0] = glo[tid]; rl0[1] = glo[tid + 512];

    ((int4*)tls)[tid] = tr0; ((int4*)tls)[tid + 512] = tr1;
    ((int4*)tls)[tid + 1024] = tr2; ((int4*)tls)[tid + 1536] = tr3;
    ((int4*)whi)[tid] = rh0[0]; ((int4*)whi)[tid + 512] = rh0[1];
    ((int4*)wlo)[tid] = rl0[0]; ((int4*)wlo)[tid + 512] = rl0[1];
    int4 rh1[2], rl1[2];
    rh1[0] = ghi[1024 + tid]; rh1[1] = ghi[1024 + tid + 512];
    rl1[0] = glo[1024 + tid]; rl1[1] = glo[1024 + tid + 512];
    __syncthreads();

    const int lane = tid & 63, wvx = tid >> 6;
    const int col = lane & 15, g = lane >> 4;
    f32x4 acc[8];
#pragma unroll
    for (int nt = 0; nt < 8; ++nt) {
        float bb = b2[nt * 16 + col];
        acc[nt] = (f32x4){bb, bb, bb, bb};
    }
    const int arow = wvx * 16 + col;
    const int aswz = (arow & 7) << 3;

#define KSTEP(k0, kk0)                                                            \
    {                                                                             \
        short8 af = *(const short8*)&tls[arow * H + (((k0) + 8 * g) ^ aswz)];     \
        _Pragma("unroll")                                                         \
        for (int nt = 0; nt < 8; ++nt) {                                          \
            int brow = nt * 16 + col;                                             \
            int bidx = brow * 64 + (((kk0) + 8 * g) ^ ((brow & 7) << 3));         \
            short8 bh = *(const short8*)&whi[bidx];                               \
            short8 bl = *(const short8*)&wlo[bidx];                               \
            acc[nt] = __builtin_amdgcn_mfma_f32_16x16x32_bf16(af, bh, acc[nt], 0, 0, 0); \
            acc[nt] = __builtin_amdgcn_mfma_f32_16x16x32_bf16(af, bl, acc[nt], 0, 0, 0); \
        }                                                                         \
    }

    __builtin_amdgcn_s_setprio(1);
    KSTEP(0, 0)
    KSTEP(32, 32)
    __builtin_amdgcn_s_setprio(0);
    __syncthreads();
    ((int4*)whi)[tid] = rh1[0]; ((int4*)whi)[tid + 512] = rh1[1];
    ((int4*)wlo)[tid] = rl1[0]; ((int4*)wlo)[tid + 512] = rl1[1];
    __syncthreads();
    __builtin_amdgcn_s_setprio(1);
    KSTEP(64, 0)
    KSTEP(96, 32)
    __builtin_amdgcn_s_setprio(0);
#undef KSTEP

    const int growbase = ebase + wvx * 16 + g * 4;
    int dr[4];
#pragma unroll
    for (int r = 0; r < 4; ++r) dr[r] = dst_c[growbase + r];
    float vrun[8];
    int dcur = dr[0];
#pragma unroll
    for (int nt = 0; nt < 8; ++nt) vrun[nt] = fmaxf(acc[nt][0], 0.f);
#pragma unroll
    for (int r = 1; r < 4; ++r) {
        if (dr[r] != dcur) {
#pragma unroll
            for (int nt = 0; nt < 8; ++nt) {
                atomicAdd(&agg[(size_t)dcur * H + nt * 16 + col], vrun[nt]);
                vrun[nt] = fmaxf(acc[nt][r], 0.f);
            }
            dcur = dr[r];
        } else {
#pragma unroll
            for (int nt = 0; nt < 8; ++nt) vrun[nt] += fmaxf(acc[nt][r], 0.f);
        }
    }
#pragma unroll
    for (int nt = 0; nt < 8; ++nt)
        atomicAdd(&agg[(size_t)dcur * H + nt * 16 + col], vrun[nt]);
}

// ---------- node: h' = relu([h,agg]@nW1+b1)@nW2+b2  (MFMA, split-bf16 weights) ----------
__global__ __launch_bounds__(512, 4) void node_mfma_kernel(
    const float* __restrict__ h, const float* __restrict__ agg,
    const ushort* __restrict__ w1h, const ushort* __restrict__ w1l,
    const ushort* __restrict__ w2h, const ushort* __restrict__ w2l,
    const float* __restrict__ b1, const float* __restrict__ b2,
    float* __restrict__ hout)
{
    __shared__ __align__(16) ushort Abuf[128 * 64];    // 16KB
    __shared__ __align__(16) ushort ubuf[128 * 128];   // 32KB
    __shared__ __align__(16) ushort Wh[128 * 64];      // 16KB
    __shared__ __align__(16) ushort Wl[128 * 64];      // 16KB
    const int tid = threadIdx.x;
    const int nbase = blockIdx.x * 128;
    const int lane = tid & 63, wvx = tid >> 6, colL = lane & 15, g = lane >> 4;
    const int arow = wvx * 16 + colL, aswz = (arow & 7) << 3;

    f32x4 acc[8];
#pragma unroll
    for (int nt = 0; nt < 8; ++nt) {
        float bb = b1[nt * 16 + colL];
        acc[nt] = (f32x4){bb, bb, bb, bb};
    }

    const int sr = tid >> 2, skq = (tid & 3) * 16;
    const int sswz = (sr & 7) << 3;
    int sn = nbase + sr; sn = sn < NN ? sn : NN - 1;

#pragma unroll
    for (int kp = 0; kp < 4; ++kp) {
        const float* srcb = (kp < 2 ? h : agg);
        const float* src = srcb + (size_t)sn * H + (kp & 1) * 64 + skq;
#pragma unroll
        for (int j = 0; j < 2; ++j) {
            float4 a = ld4(src + 8 * j);
            float4 b = ld4(src + 8 * j + 4);
            union { ushort u[8]; int4 v; } pk;
            pk.u[0] = f2bf(a.x); pk.u[1] = f2bf(a.y); pk.u[2] = f2bf(a.z); pk.u[3] = f2bf(a.w);
            pk.u[4] = f2bf(b.x); pk.u[5] = f2bf(b.y); pk.u[6] = f2bf(b.z); pk.u[7] = f2bf(b.w);
            *reinterpret_cast<int4*>(&Abuf[sr * 64 + ((skq + 8 * j) ^ sswz)]) = pk.v;
        }
        ((int4*)Wh)[tid] = ((const int4*)(w1h + kp * 8192))[tid];
        ((int4*)Wh)[tid + 512] = ((const int4*)(w1h + kp * 8192))[tid + 512];
        ((int4*)Wl)[tid] = ((const int4*)(w1l + kp * 8192))[tid];
        ((int4*)Wl)[tid + 512] = ((const int4*)(w1l + kp * 8192))[tid + 512];
        __syncthreads();
#pragma unroll
        for (int ks = 0; ks < 2; ++ks) {
            int kk0 = ks * 32;
            short8 af = *(const short8*)&Abuf[arow * 64 + ((kk0 + 8 * g) ^ aswz)];
#pragma unroll
            for (int nt = 0; nt < 8; ++nt) {
                int brow = nt * 16 + colL;
                int bidx = brow * 64 + ((kk0 + 8 * g) ^ ((brow & 7) << 3));
                short8 bh = *(const short8*)&Wh[bidx];
                short8 bl = *(const short8*)&Wl[bidx];
                acc[nt] = __builtin_amdgcn_mfma_f32_16x16x32_bf16(af, bh, acc[nt], 0, 0, 0);
                acc[nt] = __builtin_amdgcn_mfma_f32_16x16x32_bf16(af, bl, acc[nt], 0, 0, 0);
            }
        }
        __syncthreads();
    }

    const int rowb = wvx * 16 + g * 4;
#pragma unroll
    for (int r = 0; r < 4; ++r) {
        int row = rowb + r;
        int rs = (row & 7) << 3;
#pragma unroll
        for (int nt = 0; nt < 8; ++nt) {
            ubuf[row * 128 + ((nt * 16 + colL) ^ rs)] = f2bf(fmaxf(acc[nt][r], 0.f));
        }
    }
    __syncthreads();

    f32x4 acc2[8];
#pragma unroll
    for (int nt = 0; nt < 8; ++nt) {
        float bb = b2[nt * 16 + colL];
        acc2[nt] = (f32x4){bb, bb, bb, bb};
    }
#pragma unroll
    for (int kp2 = 0; kp2 < 2; ++kp2) {
        ((int4*)Wh)[tid] = ((const int4*)(w2h + kp2 * 8192))[tid];
        ((int4*)Wh)[tid + 512] = ((const int4*)(w2h + kp2 * 8192))[tid + 512];
        ((int4*)Wl)[tid] = ((const int4*)(w2l + kp2 * 8192))[tid];
        ((int4*)Wl)[tid + 512] = ((const int4*)(w2l + kp2 * 8192))[tid + 512];
        __syncthreads();
#pragma unroll
        for (int ks = 0; ks < 2; ++ks) {
            int kk0 = ks * 32;
            short8 af = *(const short8*)&ubuf[arow * 128 + ((kp2 * 64 + kk0 + 8 * g) ^ aswz)];
#pragma unroll
            for (int nt = 0; nt < 8; ++nt) {
                int brow = nt * 16 + colL;
                int bidx = brow * 64 + ((kk0 + 8 * g) ^ ((brow & 7) << 3));
                short8 bh = *(const short8*)&Wh[bidx];
                short8 bl = *(const short8*)&Wl[bidx];
                acc2[nt] = __builtin_amdgcn_mfma_f32_16x16x32_bf16(af, bh, acc2[nt], 0, 0, 0);
                acc2[nt] = __builtin_amdgcn_mfma_f32_16x16x32_bf16(af, bl, acc2[nt], 0, 0, 0);
            }
        }
        __syncthreads();
    }

#pragma unroll
    for (int r = 0; r < 4; ++r) {
        int n = nbase + rowb + r;
        if (n < NN) {
#pragma unroll
            for (int nt = 0; nt < 8; ++nt)
                hout[(size_t)n * H + nt * 16 + colL] = acc2[nt][r];
        }
    }
}

__global__ __launch_bounds__(256) void pool_kernel(const float* __restrict__ h,
    const int* __restrict__ batch, float* __restrict__ ssum,
    unsigned int* __restrict__ smaxk, float* __restrict__ cnt)
{
    const int tid = threadIdx.x, j = tid & 127, half = tid >> 7;
    const int nbase = blockIdx.x * 64;
    int cur = -1, rc = 0;
    float s = 0.f, mx = 0.f;
    for (int i = 0; i < 32; ++i) {
        int n = nbase + 2 * i + half;
        if (n >= NN) break;
        int g = batch[n];
        float v = h[(size_t)n * H + j];
        if (g != cur) {
            if (cur >= 0) {
                atomicAdd(&ssum[cur * H + j], s);
                atomicMax(&smaxk[cur * H + j], fkey(mx));
                if (j == 0) atomicAdd(&cnt[cur], (float)rc);
            }
            cur = g; s = v; mx = v; rc = 1;
        } else { s += v; mx = fmaxf(mx, v); rc++; }
    }
    if (cur >= 0) {
        atomicAdd(&ssum[cur * H + j], s);
        atomicMax(&smaxk[cur * H + j], fkey(mx));
        if (j == 0) atomicAdd(&cnt[cur], (float)rc);
    }
}

__global__ __launch_bounds__(128) void readout_kernel(const float* __restrict__ ssum,
    const unsigned int* __restrict__ smaxk, const float* __restrict__ cnt,
    const float* __restrict__ rW1, const float* __restrict__ rb1,
    const float* __restrict__ rW2, const float* __restrict__ rb2,
    const float* __restrict__ rW3, const float* __restrict__ rb3,
    float* __restrict__ out)
{
    __shared__ float p[384], h1[128], h2[64];
    const int g = blockIdx.x, j = threadIdx.x;
    float c = fmaxf(cnt[g], 1.0f);
    float sv = ssum[g * H + j];
    p[j] = sv / c;
    p[128 + j] = funkey(smaxk[g * H + j]);
    p[256 + j] = sv;
    __syncthreads();
    float a = rb1[j];
    for (int k = 0; k < 384; ++k) a = fmaf(p[k], rW1[k * H + j], a);
    h1[j] = fmaxf(a, 0.f);
    __syncthreads();
    if (j < 64) {
        float a2 = rb2[j];
        for (int k = 0; k < 128; ++k) a2 = fmaf(h1[k], rW2[k * 64 + j], a2);
        h2[j] = fmaxf(a2, 0.f);
    }
    __syncthreads();
    if (j < 64) {
        float t = h2[j] * rW3[j];
        for (int off = 32; off; off >>= 1) t += __shfl_down(t, off);
        if (j == 0) {
            float z = t + rb3[0];
            out[g] = z > 20.f ? z : log1pf(expf(z));
        }
    }
}

extern "C" void kernel_launch(void* const* d_in, const int* in_sizes, int n_in,
                              void* d_out, int out_size, void* d_ws, size_t ws_size,
                              hipStream_t stream)
{
    const float* x    = (const float*)d_in[0];
    const float* pos  = (const float*)d_in[1];
    const float* ea   = (const float*)d_in[2];
    const int*   ei   = (const int*)d_in[3];
    const int*   batch= (const int*)d_in[4];
    const float* encW = (const float*)d_in[5];
    const float* encb = (const float*)d_in[6];
    const float* eW1  = (const float*)d_in[7];
    const float* eb1  = (const float*)d_in[8];
    const float* eW2  = (const float*)d_in[9];
    const float* eb2  = (const float*)d_in[10];
    const float* nW1  = (const float*)d_in[11];
    const float* nb1  = (const float*)d_in[12];
    const float* nW2  = (const float*)d_in[13];
    const float* nb2  = (const float*)d_in[14];
    const float* rW1  = (const float*)d_in[15];
    const float* rb1  = (const float*)d_in[16];
    const float* rW2  = (const float*)d_in[17];
    const float* rb2  = (const float*)d_in[18];
    const float* rW3  = (const float*)d_in[19];
    const float* rb3  = (const float*)d_in[20];

    char* w = (char*)d_ws;
    size_t o = 0;
    auto alloc = [&](size_t bytes) -> char* {
        char* p = w + o; o += (bytes + 255) / 256 * 256; return p;
    };
    float* hA   = (float*)alloc((size_t)NN * H * 4);
    float* hB   = (float*)alloc((size_t)NN * H * 4);
    ushort* Pdb = (ushort*)alloc((size_t)NN * H * 2);
    ushort* Psb = (ushort*)alloc((size_t)NN * H * 2);
    float* agg  = (float*)alloc((size_t)NN * H * 4);
    float* d2   = (float*)alloc((size_t)NE * 4);
    float* ssum = (float*)alloc((size_t)NG * H * 4);
    unsigned int* smaxk = (unsigned int*)alloc((size_t)NG * H * 4);
    float* cnt  = (float*)alloc((size_t)NG * 4);
    int*   deg    = (int*)alloc((size_t)NN * 4);
    int*   cursor = (int*)alloc((size_t)NN * 4);
    int*   src_s  = (int*)alloc((size_t)NE * 4);
    int*   dst_s  = (int*)alloc((size_t)NE * 4);
    float* ea_s   = (float*)alloc((size_t)NE * DEA * 4);
    float* d2_s   = (float*)alloc((size_t)NE * 4);
    ushort* t_s   = (ushort*)alloc((size_t)EC * H * 2);   // 41MB chunk buffer
    ushort* w2hi  = (ushort*)alloc((size_t)NL * H * H * 2);
    ushort* w2lo  = (ushort*)alloc((size_t)NL * H * H * 2);
    ushort* nw1hi = (ushort*)alloc((size_t)NL * 256 * H * 2);
    ushort* nw1lo = (ushort*)alloc((size_t)NL * 256 * H * 2);
    ushort* nw2hi = (ushort*)alloc((size_t)NL * H * H * 2);
    ushort* nw2lo = (ushort*)alloc((size_t)NL * H * H * 2);
    ushort* w1dhi = (ushort*)alloc((size_t)NL * H * H * 2);
    ushort* w1dlo = (ushort*)alloc((size_t)NL * H * H * 2);
    ushort* w1shi = (ushort*)alloc((size_t)NL * H * H * 2);
    ushort* w1slo = (ushort*)alloc((size_t)NL * H * H * 2);
    (void)ws_size; (void)in_sizes; (void)n_in; (void)out_size;

    const int NB = (NN + 63) / 64;
    const int NBM = (NN + 127) / 128;
    const int EB = (NE + 255) / 256;

    hipMemsetAsync(deg, 0, (size_t)NN * 4, stream);
    dist2_kernel<<<EB, 256, 0, stream>>>(pos, ei, d2);
    hist_kernel<<<EB, 256, 0, stream>>>(ei, deg);
    scan_kernel<<<1, 256, 0, stream>>>(deg, cursor);
    scatter_kernel<<<EB, 256, 0, stream>>>(ei, ea, d2, cursor, src_s, dst_s, ea_s, d2_s);

    wprep_kernel<<<dim3(64, NL), 256, 0, stream>>>(eW2, w2hi, w2lo, H, H * H, H * H);
    wprep_kernel<<<dim3(128, NL), 256, 0, stream>>>(nW1, nw1hi, nw1lo, 256, 256 * H, 256 * H);
    wprep_kernel<<<dim3(64, NL), 256, 0, stream>>>(nW2, nw2hi, nw2lo, H, H * H, H * H);
    wprep_kernel<<<dim3(64, NL), 256, 0, stream>>>(eW1, w1dhi, w1dlo, H, 273 * H, H * H);
    wprep_kernel<<<dim3(64, NL), 256, 0, stream>>>(eW1 + 128 * H, w1shi, w1slo, H, 273 * H, H * H);

    encoder_kernel<<<NB, 256, 0, stream>>>(x, encW, encb, hA);

    float* hcur = hA;
    float* hnext = hB;
    for (int l = 0; l < NL; ++l) {
        hipMemsetAsync(agg, 0, (size_t)NN * H * 4, stream);
        const float* W1 = eW1 + (size_t)l * 273 * H;
        proj_mfma_kernel<<<NBM, 512, 0, stream>>>(hcur,
            w1dhi + (size_t)l * H * H, w1dlo + (size_t)l * H * H,
            w1shi + (size_t)l * H * H, w1slo + (size_t)l * H * H,
            eb1 + l * H, Pdb, Psb);
        for (int c = 0; c < NE / EC; ++c) {
            const size_t cb = (size_t)c * EC;
            tmsg_kernel<<<EC / 64, 256, 0, stream>>>(Pdb, Psb,
                ea_s + cb * DEA, d2_s + cb, src_s + cb, dst_s + cb, W1, t_s);
            agg_gemm_kernel<<<EC / EPB, 512, 0, stream>>>(t_s, dst_s + cb,
                w2hi + (size_t)l * H * H, w2lo + (size_t)l * H * H, eb2 + l * H, agg);
        }
        node_mfma_kernel<<<NBM, 512, 0, stream>>>(hcur, agg,
            nw1hi + (size_t)l * 256 * H, nw1lo + (size_t)l * 256 * H,
            nw2hi + (size_t)l * H * H, nw2lo + (size_t)l * H * H,
            nb1 + l * H, nb2 + l * H, hnext);
        float* tmp = hcur; hcur = hnext; hnext = tmp;
    }

    hipMemsetAsync(ssum, 0, (size_t)NG * H * 4, stream);
    hipMemsetAsync(smaxk, 0, (size_t)NG * H * 4, stream);
    hipMemsetAsync(cnt, 0, (size_t)NG * 4, stream);
    pool_kernel<<<NB, 256, 0, stream>>>(hcur, batch, ssum, smaxk, cnt);
    readout_kernel<<<NG, 128, 0, stream>>>(ssum, smaxk, cnt,
        rW1, rb1, rW2, rb2, rW3, rb3, (float*)d_out);
}

// Round 7
// 1975.027 us; speedup vs baseline: 1.3892x; 1.3892x over previous
//
#include <hip/hip_runtime.h>
#include <math.h>

#define NN 50000
#define NE 800000
#define NG 64
#define DIN 64
#define DEA 16
#define H 128
#define NL 4
#define EPB 128   // edges per block in edge_mfma_kernel

typedef __attribute__((ext_vector_type(8))) short short8;
typedef __attribute__((ext_vector_type(4))) float f32x4;

__device__ __forceinline__ float4 ld4(const float* p) { return *reinterpret_cast<const float4*>(p); }
__device__ __forceinline__ void st4(float* p, float4 v) { *reinterpret_cast<float4*>(p) = v; }
__device__ __forceinline__ void fma4(float4& a, float s, float4 w) {
    a.x = fmaf(s, w.x, a.x); a.y = fmaf(s, w.y, a.y);
    a.z = fmaf(s, w.z, a.z); a.w = fmaf(s, w.w, a.w);
}
__device__ __forceinline__ float4 f4add(float4 a, float4 b) {
    return make_float4(a.x + b.x, a.y + b.y, a.z + b.z, a.w + b.w);
}
__device__ __forceinline__ float4 relu4(float4 a) {
    return make_float4(fmaxf(a.x, 0.f), fmaxf(a.y, 0.f), fmaxf(a.z, 0.f), fmaxf(a.w, 0.f));
}
__device__ __forceinline__ unsigned fkey(float f) {
    unsigned b = __float_as_uint(f);
    return (b & 0x80000000u) ? ~b : (b | 0x80000000u);
}
__device__ __forceinline__ float funkey(unsigned k) {
    unsigned b = (k & 0x80000000u) ? (k ^ 0x80000000u) : ~k;
    return __uint_as_float(b);
}
__device__ __forceinline__ ushort f2bf(float f) {
    unsigned u = __float_as_uint(f);
    return (ushort)((u + 0x7fffu + ((u >> 16) & 1u)) >> 16);
}
__device__ __forceinline__ float bf2f(ushort b) {
    return __uint_as_float(((unsigned)b) << 16);
}

// h = relu(x @ encW + encb), x:[NN,64], W:[64,128]
__global__ __launch_bounds__(256) void encoder_kernel(const float* __restrict__ x,
    const float* __restrict__ W, const float* __restrict__ b, float* __restrict__ h)
{
    const int tid = threadIdx.x, q = tid & 31, no = tid >> 5;
    const int nbase = blockIdx.x * 64;
    float4 bv = ld4(b + 4 * q);
    float4 acc[8];
#pragma unroll
    for (int i = 0; i < 8; ++i) acc[i] = bv;
    for (int k4 = 0; k4 < 16; ++k4) {
        const float* wp = W + (4 * k4) * H + 4 * q;
        float4 w0 = ld4(wp), w1 = ld4(wp + H), w2 = ld4(wp + 2 * H), w3 = ld4(wp + 3 * H);
#pragma unroll
        for (int i = 0; i < 8; ++i) {
            int n = nbase + no * 8 + i; n = n < NN ? n : NN - 1;
            float4 a = ld4(x + n * DIN + 4 * k4);
            fma4(acc[i], a.x, w0); fma4(acc[i], a.y, w1);
            fma4(acc[i], a.z, w2); fma4(acc[i], a.w, w3);
        }
    }
#pragma unroll
    for (int i = 0; i < 8; ++i) {
        int n = nbase + no * 8 + i;
        if (n < NN) st4(h + n * H + 4 * q, relu4(acc[i]));
    }
}

__global__ __launch_bounds__(256) void dist2_kernel(const float* __restrict__ pos,
    const int* __restrict__ ei, float* __restrict__ d2)
{
    int e = blockIdx.x * 256 + threadIdx.x;
    if (e >= NE) return;
    int s = ei[e], d = ei[NE + e];
    float dx = pos[s * 3 + 0] - pos[d * 3 + 0];
    float dy = pos[s * 3 + 1] - pos[d * 3 + 1];
    float dz = pos[s * 3 + 2] - pos[d * 3 + 2];
    d2[e] = dx * dx + dy * dy + dz * dz;
}

// ---------- counting sort of edges by dst ----------
__global__ __launch_bounds__(256) void hist_kernel(const int* __restrict__ ei, int* __restrict__ deg)
{
    int e = blockIdx.x * 256 + threadIdx.x;
    if (e < NE) atomicAdd(&deg[ei[NE + e]], 1);
}

// single block, 1024 threads: exclusive scan of deg[NN] -> cursor
__global__ __launch_bounds__(1024) void scan_kernel(const int* __restrict__ deg, int* __restrict__ cursor)
{
    __shared__ int tot[1024];
    const int t = threadIdx.x;
    const int CH = (NN + 1023) / 1024;   // 49
    const int base = t * CH;
    int s = 0;
    for (int i = 0; i < CH; ++i) {
        int idx = base + i;
        if (idx < NN) s += deg[idx];
    }
    tot[t] = s;
    __syncthreads();
    for (int off = 1; off < 1024; off <<= 1) {
        int v = (t >= off) ? tot[t - off] : 0;
        __syncthreads();
        tot[t] += v;
        __syncthreads();
    }
    int run = (t == 0) ? 0 : tot[t - 1];
    for (int i = 0; i < CH; ++i) {
        int idx = base + i;
        if (idx < NN) { cursor[idx] = run; run += deg[idx]; }
    }
}

__global__ __launch_bounds__(256) void scatter_kernel(const int* __restrict__ ei,
    const float* __restrict__ ea, const float* __restrict__ d2, int* __restrict__ cursor,
    int* __restrict__ src_s, int* __restrict__ dst_s,
    float* __restrict__ ea_s, float* __restrict__ d2_s)
{
    int e = blockIdx.x * 256 + threadIdx.x;
    if (e >= NE) return;
    int s = ei[e], d = ei[NE + e];
    int pos = atomicAdd(&cursor[d], 1);
    src_s[pos] = s; dst_s[pos] = d; d2_s[pos] = d2[e];
    const float4* ev = reinterpret_cast<const float4*>(ea + (size_t)e * DEA);
    float4* ov = reinterpret_cast<float4*>(ea_s + (size_t)pos * DEA);
    ov[0] = ev[0]; ov[1] = ev[1]; ov[2] = ev[2]; ov[3] = ev[3];
}

// ---------- generic W [K x 128] -> split bf16 (hi+lo), transposed [n][k], k-panel-64 swizzled ----------
__global__ __launch_bounds__(256) void wprep_kernel(const float* __restrict__ W,
    ushort* __restrict__ hi, ushort* __restrict__ lo,
    int K, int in_lstride, int out_lstride)
{
    int l = blockIdx.y;
    const float* Wb = W + (size_t)l * in_lstride;
    ushort* hg = hi + (size_t)l * out_lstride;
    ushort* lg = lo + (size_t)l * out_lstride;
    int total = K * 128;
    for (int idx = blockIdx.x * 256 + threadIdx.x; idx < total; idx += gridDim.x * 256) {
        int k = idx >> 7, n = idx & 127;
        float wv = Wb[idx];
        ushort hb = f2bf(wv);
        float rem = wv - bf2f(hb);
        ushort lb = f2bf(rem);
        int panel = k >> 6, kk = k & 63;
        int pos = panel * 8192 + (n << 6) + (kk ^ ((n & 7) << 3));
        hg[pos] = hb; lg[pos] = lb;
    }
}

// ---------- proj: Pdb = bf16(h@W1d + b1), Psb = bf16(h@W1s)  (MFMA, split-bf16 weights) ----------
__global__ __launch_bounds__(512, 4) void proj_mfma_kernel(const float* __restrict__ h,
    const ushort* __restrict__ wdh, const ushort* __restrict__ wdl,
    const ushort* __restrict__ wsh, const ushort* __restrict__ wsl,
    const float* __restrict__ b1,
    ushort* __restrict__ Pdb, ushort* __restrict__ Psb)
{
    __shared__ __align__(16) ushort Afull[128 * 128];  // 32KB
    __shared__ __align__(16) ushort Wh[128 * 64];      // 16KB
    __shared__ __align__(16) ushort Wl[128 * 64];      // 16KB
    const int tid = threadIdx.x;
    const int nbase = blockIdx.x * 128;

    {
        int r = tid >> 2, kq = (tid & 3) * 32;
        int n = nbase + r; n = n < NN ? n : NN - 1;
        const float* src = h + (size_t)n * H + kq;
        int swz = (r & 7) << 3;
#pragma unroll
        for (int j = 0; j < 4; ++j) {
            float4 a = ld4(src + 8 * j);
            float4 b = ld4(src + 8 * j + 4);
            union { ushort u[8]; int4 v; } pk;
            pk.u[0] = f2bf(a.x); pk.u[1] = f2bf(a.y); pk.u[2] = f2bf(a.z); pk.u[3] = f2bf(a.w);
            pk.u[4] = f2bf(b.x); pk.u[5] = f2bf(b.y); pk.u[6] = f2bf(b.z); pk.u[7] = f2bf(b.w);
            *reinterpret_cast<int4*>(&Afull[r * 128 + ((kq + 8 * j) ^ swz)]) = pk.v;
        }
    }

    const int lane = tid & 63, wvx = tid >> 6, colL = lane & 15, g = lane >> 4;
    const int arow = wvx * 16 + colL, aswz = (arow & 7) << 3;
    f32x4 accd[8], accs[8];
#pragma unroll
    for (int nt = 0; nt < 8; ++nt) { accd[nt] = (f32x4){0, 0, 0, 0}; accs[nt] = (f32x4){0, 0, 0, 0}; }

#define PROJ_ROUND(HSRC, LSRC, KOFF, ACC)                                               \
    {                                                                                   \
        ((int4*)Wh)[tid] = ((const int4*)(HSRC))[tid];                                  \
        ((int4*)Wh)[tid + 512] = ((const int4*)(HSRC))[tid + 512];                      \
        ((int4*)Wl)[tid] = ((const int4*)(LSRC))[tid];                                  \
        ((int4*)Wl)[tid + 512] = ((const int4*)(LSRC))[tid + 512];                      \
        __syncthreads();                                                                \
        _Pragma("unroll")                                                               \
        for (int ks = 0; ks < 2; ++ks) {                                                \
            int kk0 = ks * 32;                                                          \
            short8 af = *(const short8*)&Afull[arow * 128 + (((KOFF) + kk0 + 8 * g) ^ aswz)]; \
            _Pragma("unroll")                                                           \
            for (int nt = 0; nt < 8; ++nt) {                                            \
                int brow = nt * 16 + colL;                                              \
                int bidx = brow * 64 + ((kk0 + 8 * g) ^ ((brow & 7) << 3));             \
                short8 bh = *(const short8*)&Wh[bidx];                                  \
                short8 bl = *(const short8*)&Wl[bidx];                                  \
                ACC[nt] = __builtin_amdgcn_mfma_f32_16x16x32_bf16(af, bh, ACC[nt], 0, 0, 0); \
                ACC[nt] = __builtin_amdgcn_mfma_f32_16x16x32_bf16(af, bl, ACC[nt], 0, 0, 0); \
            }                                                                           \
        }                                                                               \
        __syncthreads();                                                                \
    }

    PROJ_ROUND(wdh, wdl, 0, accd)
    PROJ_ROUND(wdh + 8192, wdl + 8192, 64, accd)
    PROJ_ROUND(wsh, wsl, 0, accs)
    PROJ_ROUND(wsh + 8192, wsl + 8192, 64, accs)
#undef PROJ_ROUND

    float b1r[8];
#pragma unroll
    for (int nt = 0; nt < 8; ++nt) b1r[nt] = b1[nt * 16 + colL];

    const int rowb = wvx * 16 + g * 4;
#pragma unroll
    for (int r = 0; r < 4; ++r) {
        int n = nbase + rowb + r;
        if (n < NN) {
#pragma unroll
            for (int nt = 0; nt < 8; ++nt) {
                Pdb[(size_t)n * H + nt * 16 + colL] = f2bf(accd[nt][r] + b1r[nt]);
                Psb[(size_t)n * H + nt * 16 + colL] = f2bf(accs[nt][r]);
            }
        }
    }
}

// dst-sorted edges, 128 edges/block, 8 waves, fused.
// stage1 (fp32 VALU, bf16 gathers): t = relu(Pdb[dst]+Psb[src]+d2*wd+ea@Wea) -> bf16 swizzled LDS
// stage2 (MFMA bf16, 4 single-buffer W passes: hi-k0, hi-k1, lo-k0, lo-k1): m = relu(t@W2+b2)
// LDS = 32KB tls + 16KB wbuf = 48KB -> 3 blocks/CU target
__global__ __launch_bounds__(512, 4) void edge_mfma_kernel(
    const ushort* __restrict__ Pdb, const ushort* __restrict__ Psb,
    const float* __restrict__ ea_s, const float* __restrict__ d2_s,
    const int* __restrict__ src_s, const int* __restrict__ dst_s,
    const float* __restrict__ W1,
    const ushort* __restrict__ w2hiL, const ushort* __restrict__ w2loL,
    const float* __restrict__ b2, float* __restrict__ agg)
{
    __shared__ __align__(16) ushort tls[EPB * H];   // 32KB
    __shared__ __align__(16) ushort wbuf[H * 64];   // 16KB, cycled through 4 panels

    const int tid = threadIdx.x, q = tid & 31, eo = tid >> 5;
    const int ebase = blockIdx.x * EPB;

    const int4* ghi = (const int4*)w2hiL;
    const int4* glo = (const int4*)w2loL;
    // prefetch panel 0 (hi, k-half 0)
    int4 p0a = ghi[tid], p0b = ghi[tid + 512];

    // ---- stage 1: edge MLP layer-1 (fp32, bf16 gathers) ----
    const float* Wea = W1 + 256 * H;
    const float* wdv = W1 + 272 * H;
    float4 wdq = ld4(wdv + 4 * q);

    int srcs[8], dsts8[8];
    float d2v[8];
#pragma unroll
    for (int i = 0; i < 8; ++i) {
        int j = ebase + eo * 8 + i;
        srcs[i] = src_s[j]; dsts8[i] = dst_s[j]; d2v[i] = d2_s[j];
    }
    float4 acc1[8];
#pragma unroll
    for (int i = 0; i < 8; ++i) {
        ushort4 pd4 = *reinterpret_cast<const ushort4*>(&Pdb[(size_t)dsts8[i] * H + 4 * q]);
        ushort4 ps4 = *reinterpret_cast<const ushort4*>(&Psb[(size_t)srcs[i] * H + 4 * q]);
        float4 a;
        a.x = bf2f(pd4.x) + bf2f(ps4.x);
        a.y = bf2f(pd4.y) + bf2f(ps4.y);
        a.z = bf2f(pd4.z) + bf2f(ps4.z);
        a.w = bf2f(pd4.w) + bf2f(ps4.w);
        fma4(a, d2v[i], wdq);
        acc1[i] = a;
    }
#pragma unroll
    for (int k4 = 0; k4 < 4; ++k4) {
        float4 w0 = ld4(Wea + (4 * k4 + 0) * H + 4 * q);
        float4 w1 = ld4(Wea + (4 * k4 + 1) * H + 4 * q);
        float4 w2 = ld4(Wea + (4 * k4 + 2) * H + 4 * q);
        float4 w3 = ld4(Wea + (4 * k4 + 3) * H + 4 * q);
#pragma unroll
        for (int i = 0; i < 8; ++i) {
            int j = ebase + eo * 8 + i;
            float4 av = ld4(ea_s + (size_t)j * DEA + 4 * k4);
            fma4(acc1[i], av.x, w0); fma4(acc1[i], av.y, w1);
            fma4(acc1[i], av.z, w2); fma4(acc1[i], av.w, w3);
        }
    }
#pragma unroll
    for (int i = 0; i < 8; ++i) {
        int el = eo * 8 + i;
        ushort4 tv;
        tv.x = f2bf(fmaxf(acc1[i].x, 0.f)); tv.y = f2bf(fmaxf(acc1[i].y, 0.f));
        tv.z = f2bf(fmaxf(acc1[i].z, 0.f)); tv.w = f2bf(fmaxf(acc1[i].w, 0.f));
        int tidx = el * H + ((4 * q) ^ ((el & 7) << 3));
        *reinterpret_cast<ushort4*>(&tls[tidx]) = tv;
    }

    // ---- stage 2: MFMA t @ W2, 4 panel passes through one 16KB buffer ----
    const int lane = tid & 63, wvx = tid >> 6;
    const int col = lane & 15, g = lane >> 4;
    f32x4 acc[8];
#pragma unroll
    for (int nt = 0; nt < 8; ++nt) {
        float bb = b2[nt * 16 + col];
        acc[nt] = (f32x4){bb, bb, bb, bb};
    }
    const int arow = wvx * 16 + col;
    const int aswz = (arow & 7) << 3;

#define KSTEP1(k0, kk0)                                                           \
    {                                                                             \
        short8 af = *(const short8*)&tls[arow * H + (((k0) + 8 * g) ^ aswz)];     \
        _Pragma("unroll")                                                         \
        for (int nt = 0; nt < 8; ++nt) {                                          \
            int brow = nt * 16 + col;                                             \
            int bidx = brow * 64 + (((kk0) + 8 * g) ^ ((brow & 7) << 3));         \
            short8 bw = *(const short8*)&wbuf[bidx];                              \
            acc[nt] = __builtin_amdgcn_mfma_f32_16x16x32_bf16(af, bw, acc[nt], 0, 0, 0); \
        }                                                                         \
    }

    // panel 0: hi, k 0..63
    ((int4*)wbuf)[tid] = p0a; ((int4*)wbuf)[tid + 512] = p0b;
    int4 p1a = ghi[1024 + tid], p1b = ghi[1024 + tid + 512];   // prefetch hi k-half 1
    __syncthreads();
    __builtin_amdgcn_s_setprio(1);
    KSTEP1(0, 0)
    KSTEP1(32, 32)
    __builtin_amdgcn_s_setprio(0);
    __syncthreads();

    // panel 1: hi, k 64..127
    ((int4*)wbuf)[tid] = p1a; ((int4*)wbuf)[tid + 512] = p1b;
    int4 p2a = glo[tid], p2b = glo[tid + 512];                 // prefetch lo k-half 0
    __syncthreads();
    __builtin_amdgcn_s_setprio(1);
    KSTEP1(64, 0)
    KSTEP1(96, 32)
    __builtin_amdgcn_s_setprio(0);
    __syncthreads();

    // panel 2: lo, k 0..63
    ((int4*)wbuf)[tid] = p2a; ((int4*)wbuf)[tid + 512] = p2b;
    int4 p3a = glo[1024 + tid], p3b = glo[1024 + tid + 512];   // prefetch lo k-half 1
    __syncthreads();
    __builtin_amdgcn_s_setprio(1);
    KSTEP1(0, 0)
    KSTEP1(32, 32)
    __builtin_amdgcn_s_setprio(0);
    __syncthreads();

    // panel 3: lo, k 64..127
    ((int4*)wbuf)[tid] = p3a; ((int4*)wbuf)[tid + 512] = p3b;
    __syncthreads();
    __builtin_amdgcn_s_setprio(1);
    KSTEP1(64, 0)
    KSTEP1(96, 32)
    __builtin_amdgcn_s_setprio(0);
#undef KSTEP1

    // ---- segmented atomic flush ----
    const int growbase = ebase + wvx * 16 + g * 4;
    int dr[4];
#pragma unroll
    for (int r = 0; r < 4; ++r) dr[r] = dst_s[growbase + r];
    float vrun[8];
    int dcur = dr[0];
#pragma unroll
    for (int nt = 0; nt < 8; ++nt) vrun[nt] = fmaxf(acc[nt][0], 0.f);
#pragma unroll
    for (int r = 1; r < 4; ++r) {
        if (dr[r] != dcur) {
#pragma unroll
            for (int nt = 0; nt < 8; ++nt) {
                atomicAdd(&agg[(size_t)dcur * H + nt * 16 + col], vrun[nt]);
                vrun[nt] = fmaxf(acc[nt][r], 0.f);
            }
            dcur = dr[r];
        } else {
#pragma unroll
            for (int nt = 0; nt < 8; ++nt) vrun[nt] += fmaxf(acc[nt][r], 0.f);
        }
    }
#pragma unroll
    for (int nt = 0; nt < 8; ++nt)
        atomicAdd(&agg[(size_t)dcur * H + nt * 16 + col], vrun[nt]);
}

// ---------- node: h' = relu([h,agg]@nW1+b1)@nW2+b2  (MFMA, split-bf16 weights) ----------
__global__ __launch_bounds__(512, 4) void node_mfma_kernel(
    const float* __restrict__ h, const float* __restrict__ agg,
    const ushort* __restrict__ w1h, const ushort* __restrict__ w1l,
    const ushort* __restrict__ w2h, const ushort* __restrict__ w2l,
    const float* __restrict__ b1, const float* __restrict__ b2,
    float* __restrict__ hout)
{
    __shared__ __align__(16) ushort Abuf[128 * 64];    // 16KB
    __shared__ __align__(16) ushort ubuf[128 * 128];   // 32KB
    __shared__ __align__(16) ushort Wh[128 * 64];      // 16KB
    __shared__ __align__(16) ushort Wl[128 * 64];      // 16KB
    const int tid = threadIdx.x;
    const int nbase = blockIdx.x * 128;
    const int lane = tid & 63, wvx = tid >> 6, colL = lane & 15, g = lane >> 4;
    const int arow = wvx * 16 + colL, aswz = (arow & 7) << 3;

    f32x4 acc[8];
#pragma unroll
    for (int nt = 0; nt < 8; ++nt) {
        float bb = b1[nt * 16 + colL];
        acc[nt] = (f32x4){bb, bb, bb, bb};
    }

    const int sr = tid >> 2, skq = (tid & 3) * 16;
    const int sswz = (sr & 7) << 3;
    int sn = nbase + sr; sn = sn < NN ? sn : NN - 1;

#pragma unroll
    for (int kp = 0; kp < 4; ++kp) {
        const float* srcb = (kp < 2 ? h : agg);
        const float* src = srcb + (size_t)sn * H + (kp & 1) * 64 + skq;
#pragma unroll
        for (int j = 0; j < 2; ++j) {
            float4 a = ld4(src + 8 * j);
            float4 b = ld4(src + 8 * j + 4);
            union { ushort u[8]; int4 v; } pk;
            pk.u[0] = f2bf(a.x); pk.u[1] = f2bf(a.y); pk.u[2] = f2bf(a.z); pk.u[3] = f2bf(a.w);
            pk.u[4] = f2bf(b.x); pk.u[5] = f2bf(b.y); pk.u[6] = f2bf(b.z); pk.u[7] = f2bf(b.w);
            *reinterpret_cast<int4*>(&Abuf[sr * 64 + ((skq + 8 * j) ^ sswz)]) = pk.v;
        }
        ((int4*)Wh)[tid] = ((const int4*)(w1h + kp * 8192))[tid];
        ((int4*)Wh)[tid + 512] = ((const int4*)(w1h + kp * 8192))[tid + 512];
        ((int4*)Wl)[tid] = ((const int4*)(w1l + kp * 8192))[tid];
        ((int4*)Wl)[tid + 512] = ((const int4*)(w1l + kp * 8192))[tid + 512];
        __syncthreads();
#pragma unroll
        for (int ks = 0; ks < 2; ++ks) {
            int kk0 = ks * 32;
            short8 af = *(const short8*)&Abuf[arow * 64 + ((kk0 + 8 * g) ^ aswz)];
#pragma unroll
            for (int nt = 0; nt < 8; ++nt) {
                int brow = nt * 16 + colL;
                int bidx = brow * 64 + ((kk0 + 8 * g) ^ ((brow & 7) << 3));
                short8 bh = *(const short8*)&Wh[bidx];
                short8 bl = *(const short8*)&Wl[bidx];
                acc[nt] = __builtin_amdgcn_mfma_f32_16x16x32_bf16(af, bh, acc[nt], 0, 0, 0);
                acc[nt] = __builtin_amdgcn_mfma_f32_16x16x32_bf16(af, bl, acc[nt], 0, 0, 0);
            }
        }
        __syncthreads();
    }

    const int rowb = wvx * 16 + g * 4;
#pragma unroll
    for (int r = 0; r < 4; ++r) {
        int row = rowb + r;
        int rs = (row & 7) << 3;
#pragma unroll
        for (int nt = 0; nt < 8; ++nt) {
            ubuf[row * 128 + ((nt * 16 + colL) ^ rs)] = f2bf(fmaxf(acc[nt][r], 0.f));
        }
    }
    __syncthreads();

    f32x4 acc2[8];
#pragma unroll
    for (int nt = 0; nt < 8; ++nt) {
        float bb = b2[nt * 16 + colL];
        acc2[nt] = (f32x4){bb, bb, bb, bb};
    }
#pragma unroll
    for (int kp2 = 0; kp2 < 2; ++kp2) {
        ((int4*)Wh)[tid] = ((const int4*)(w2h + kp2 * 8192))[tid];
        ((int4*)Wh)[tid + 512] = ((const int4*)(w2h + kp2 * 8192))[tid + 512];
        ((int4*)Wl)[tid] = ((const int4*)(w2l + kp2 * 8192))[tid];
        ((int4*)Wl)[tid + 512] = ((const int4*)(w2l + kp2 * 8192))[tid + 512];
        __syncthreads();
#pragma unroll
        for (int ks = 0; ks < 2; ++ks) {
            int kk0 = ks * 32;
            short8 af = *(const short8*)&ubuf[arow * 128 + ((kp2 * 64 + kk0 + 8 * g) ^ aswz)];
#pragma unroll
            for (int nt = 0; nt < 8; ++nt) {
                int brow = nt * 16 + colL;
                int bidx = brow * 64 + ((kk0 + 8 * g) ^ ((brow & 7) << 3));
                short8 bh = *(const short8*)&Wh[bidx];
                short8 bl = *(const short8*)&Wl[bidx];
                acc2[nt] = __builtin_amdgcn_mfma_f32_16x16x32_bf16(af, bh, acc2[nt], 0, 0, 0);
                acc2[nt] = __builtin_amdgcn_mfma_f32_16x16x32_bf16(af, bl, acc2[nt], 0, 0, 0);
            }
        }
        __syncthreads();
    }

#pragma unroll
    for (int r = 0; r < 4; ++r) {
        int n = nbase + rowb + r;
        if (n < NN) {
#pragma unroll
            for (int nt = 0; nt < 8; ++nt)
                hout[(size_t)n * H + nt * 16 + colL] = acc2[nt][r];
        }
    }
}

__global__ __launch_bounds__(256) void pool_kernel(const float* __restrict__ h,
    const int* __restrict__ batch, float* __restrict__ ssum,
    unsigned int* __restrict__ smaxk, float* __restrict__ cnt)
{
    const int tid = threadIdx.x, j = tid & 127, half = tid >> 7;
    const int nbase = blockIdx.x * 64;
    int cur = -1, rc = 0;
    float s = 0.f, mx = 0.f;
    for (int i = 0; i < 32; ++i) {
        int n = nbase + 2 * i + half;
        if (n >= NN) break;
        int g = batch[n];
        float v = h[(size_t)n * H + j];
        if (g != cur) {
            if (cur >= 0) {
                atomicAdd(&ssum[cur * H + j], s);
                atomicMax(&smaxk[cur * H + j], fkey(mx));
                if (j == 0) atomicAdd(&cnt[cur], (float)rc);
            }
            cur = g; s = v; mx = v; rc = 1;
        } else { s += v; mx = fmaxf(mx, v); rc++; }
    }
    if (cur >= 0) {
        atomicAdd(&ssum[cur * H + j], s);
        atomicMax(&smaxk[cur * H + j], fkey(mx));
        if (j == 0) atomicAdd(&cnt[cur], (float)rc);
    }
}

__global__ __launch_bounds__(128) void readout_kernel(const float* __restrict__ ssum,
    const unsigned int* __restrict__ smaxk, const float* __restrict__ cnt,
    const float* __restrict__ rW1, const float* __restrict__ rb1,
    const float* __restrict__ rW2, const float* __restrict__ rb2,
    const float* __restrict__ rW3, const float* __restrict__ rb3,
    float* __restrict__ out)
{
    __shared__ float p[384], h1[128], h2[64];
    const int g = blockIdx.x, j = threadIdx.x;
    float c = fmaxf(cnt[g], 1.0f);
    float sv = ssum[g * H + j];
    p[j] = sv / c;
    p[128 + j] = funkey(smaxk[g * H + j]);
    p[256 + j] = sv;
    __syncthreads();
    float a = rb1[j];
    for (int k = 0; k < 384; ++k) a = fmaf(p[k], rW1[k * H + j], a);
    h1[j] = fmaxf(a, 0.f);
    __syncthreads();
    if (j < 64) {
        float a2 = rb2[j];
        for (int k = 0; k < 128; ++k) a2 = fmaf(h1[k], rW2[k * 64 + j], a2);
        h2[j] = fmaxf(a2, 0.f);
    }
    __syncthreads();
    if (j < 64) {
        float t = h2[j] * rW3[j];
        for (int off = 32; off; off >>= 1) t += __shfl_down(t, off);
        if (j == 0) {
            float z = t + rb3[0];
            out[g] = z > 20.f ? z : log1pf(expf(z));
        }
    }
}

extern "C" void kernel_launch(void* const* d_in, const int* in_sizes, int n_in,
                              void* d_out, int out_size, void* d_ws, size_t ws_size,
                              hipStream_t stream)
{
    const float* x    = (const float*)d_in[0];
    const float* pos  = (const float*)d_in[1];
    const float* ea   = (const float*)d_in[2];
    const int*   ei   = (const int*)d_in[3];
    const int*   batch= (const int*)d_in[4];
    const float* encW = (const float*)d_in[5];
    const float* encb = (const float*)d_in[6];
    const float* eW1  = (const float*)d_in[7];
    const float* eb1  = (const float*)d_in[8];
    const float* eW2  = (const float*)d_in[9];
    const float* eb2  = (const float*)d_in[10];
    const float* nW1  = (const float*)d_in[11];
    const float* nb1  = (const float*)d_in[12];
    const float* nW2  = (const float*)d_in[13];
    const float* nb2  = (const float*)d_in[14];
    const float* rW1  = (const float*)d_in[15];
    const float* rb1  = (const float*)d_in[16];
    const float* rW2  = (const float*)d_in[17];
    const float* rb2  = (const float*)d_in[18];
    const float* rW3  = (const float*)d_in[19];
    const float* rb3  = (const float*)d_in[20];

    char* w = (char*)d_ws;
    size_t o = 0;
    auto alloc = [&](size_t bytes) -> char* {
        char* p = w + o; o += (bytes + 255) / 256 * 256; return p;
    };
    float* hA   = (float*)alloc((size_t)NN * H * 4);
    float* hB   = (float*)alloc((size_t)NN * H * 4);
    ushort* Pdb = (ushort*)alloc((size_t)NN * H * 2);
    ushort* Psb = (ushort*)alloc((size_t)NN * H * 2);
    float* agg  = (float*)alloc((size_t)NN * H * 4);
    float* d2   = (float*)alloc((size_t)NE * 4);
    float* ssum = (float*)alloc((size_t)NG * H * 4);
    unsigned int* smaxk = (unsigned int*)alloc((size_t)NG * H * 4);
    float* cnt  = (float*)alloc((size_t)NG * 4);
    int*   deg    = (int*)alloc((size_t)NN * 4);
    int*   cursor = (int*)alloc((size_t)NN * 4);
    int*   src_s  = (int*)alloc((size_t)NE * 4);
    int*   dst_s  = (int*)alloc((size_t)NE * 4);
    float* ea_s   = (float*)alloc((size_t)NE * DEA * 4);
    float* d2_s   = (float*)alloc((size_t)NE * 4);
    ushort* w2hi  = (ushort*)alloc((size_t)NL * H * H * 2);
    ushort* w2lo  = (ushort*)alloc((size_t)NL * H * H * 2);
    ushort* nw1hi = (ushort*)alloc((size_t)NL * 256 * H * 2);
    ushort* nw1lo = (ushort*)alloc((size_t)NL * 256 * H * 2);
    ushort* nw2hi = (ushort*)alloc((size_t)NL * H * H * 2);
    ushort* nw2lo = (ushort*)alloc((size_t)NL * H * H * 2);
    ushort* w1dhi = (ushort*)alloc((size_t)NL * H * H * 2);
    ushort* w1dlo = (ushort*)alloc((size_t)NL * H * H * 2);
    ushort* w1shi = (ushort*)alloc((size_t)NL * H * H * 2);
    ushort* w1slo = (ushort*)alloc((size_t)NL * H * H * 2);
    (void)ws_size; (void)in_sizes; (void)n_in; (void)out_size;

    const int NB = (NN + 63) / 64;
    const int NBM = (NN + 127) / 128;
    const int EB = (NE + 255) / 256;

    hipMemsetAsync(deg, 0, (size_t)NN * 4, stream);
    dist2_kernel<<<EB, 256, 0, stream>>>(pos, ei, d2);
    hist_kernel<<<EB, 256, 0, stream>>>(ei, deg);
    scan_kernel<<<1, 1024, 0, stream>>>(deg, cursor);
    scatter_kernel<<<EB, 256, 0, stream>>>(ei, ea, d2, cursor, src_s, dst_s, ea_s, d2_s);

    wprep_kernel<<<dim3(64, NL), 256, 0, stream>>>(eW2, w2hi, w2lo, H, H * H, H * H);
    wprep_kernel<<<dim3(128, NL), 256, 0, stream>>>(nW1, nw1hi, nw1lo, 256, 256 * H, 256 * H);
    wprep_kernel<<<dim3(64, NL), 256, 0, stream>>>(nW2, nw2hi, nw2lo, H, H * H, H * H);
    wprep_kernel<<<dim3(64, NL), 256, 0, stream>>>(eW1, w1dhi, w1dlo, H, 273 * H, H * H);
    wprep_kernel<<<dim3(64, NL), 256, 0, stream>>>(eW1 + 128 * H, w1shi, w1slo, H, 273 * H, H * H);

    encoder_kernel<<<NB, 256, 0, stream>>>(x, encW, encb, hA);

    float* hcur = hA;
    float* hnext = hB;
    for (int l = 0; l < NL; ++l) {
        hipMemsetAsync(agg, 0, (size_t)NN * H * 4, stream);
        const float* W1 = eW1 + (size_t)l * 273 * H;
        proj_mfma_kernel<<<NBM, 512, 0, stream>>>(hcur,
            w1dhi + (size_t)l * H * H, w1dlo + (size_t)l * H * H,
            w1shi + (size_t)l * H * H, w1slo + (size_t)l * H * H,
            eb1 + l * H, Pdb, Psb);
        edge_mfma_kernel<<<NE / EPB, 512, 0, stream>>>(Pdb, Psb, ea_s, d2_s, src_s, dst_s,
            W1, w2hi + (size_t)l * H * H, w2lo + (size_t)l * H * H,
            eb2 + l * H, agg);
        node_mfma_kernel<<<NBM, 512, 0, stream>>>(hcur, agg,
            nw1hi + (size_t)l * 256 * H, nw1lo + (size_t)l * 256 * H,
            nw2hi + (size_t)l * H * H, nw2lo + (size_t)l * H * H,
            nb1 + l * H, nb2 + l * H, hnext);
        float* tmp = hcur; hcur = hnext; hnext = tmp;
    }

    hipMemsetAsync(ssum, 0, (size_t)NG * H * 4, stream);
    hipMemsetAsync(smaxk, 0, (size_t)NG * H * 4, stream);
    hipMemsetAsync(cnt, 0, (size_t)NG * 4, stream);
    pool_kernel<<<NB, 256, 0, stream>>>(hcur, batch, ssum, smaxk, cnt);
    readout_kernel<<<NG, 128, 0, stream>>>(ssum, smaxk, cnt,
        rW1, rb1, rW2, rb2, rW3, rb3, (float*)d_out);
}